// Round 3
// baseline (669.841 us; speedup 1.0000x reference)
//
#include <hip/hip_runtime.h>
#include <math.h>

typedef unsigned short u16;
typedef short short8 __attribute__((ext_vector_type(8)));
typedef float f32x4 __attribute__((ext_vector_type(4)));

#define TT 4
#define BB 4096
#define DIM 512
#define HDIM 1024
#define BD (BB*DIM)      // 2097152
#define D2 (DIM*DIM)     // 262144
#define NEXP 20

#define GLOAD16(gp, lp) __builtin_amdgcn_global_load_lds( \
    (__attribute__((address_space(1))) void*)(void*)(gp), \
    (__attribute__((address_space(3))) void*)(void*)(lp), 16, 0, 0)

__device__ __forceinline__ u16 f2b(float f) {
  union { float f; unsigned u; } x; x.f = f;
  unsigned r = x.u + 0x7FFFu + ((x.u >> 16) & 1u);
  return (u16)(r >> 16);
}
__device__ __forceinline__ float b2f(u16 v) {
  union { unsigned u; float f; } x; x.u = ((unsigned)v) << 16; return x.f;
}

__device__ __forceinline__ float wsum(float v) {
#pragma unroll
  for (int o = 32; o > 0; o >>= 1) v += __shfl_xor(v, o);
  return v;
}

// fast exact-enough GELU
__device__ __forceinline__ float fgelu(float v) {
  float u = 1.5957691216057308f * v * (1.0f + 0.044715f * v * v);
  return v / (1.0f + __expf(-u));
}

// ------ prep: one wave per row b: mean, bf16 casts, score-bias sbias --------
__global__ __launch_bounds__(256) void k_prep(const float* __restrict__ ti,
                                              const float* __restrict__ qwkb,
                                              const float* __restrict__ kbqb,
                                              u16* __restrict__ tib,
                                              u16* __restrict__ xsb,
                                              float* __restrict__ sbias) {
  int gw = (blockIdx.x * 256 + threadIdx.x) >> 6;   // row b
  int lane = threadIdx.x & 63;
  int d0 = lane * 8;
  float x[4][8];
#pragma unroll
  for (int t = 0; t < 4; t++) {
    const float* p = ti + ((size_t)t * BB + gw) * DIM + d0;
    *(float4*)&x[t][0] = *(const float4*)p;
    *(float4*)&x[t][4] = *(const float4*)(p + 4);
  }
  float m[8];
#pragma unroll
  for (int j = 0; j < 8; j++)
    m[j] = (x[0][j] + x[1][j] + x[2][j] + x[3][j]) * 0.25f;
#pragma unroll
  for (int t = 0; t < 4; t++) {
    ushort4 c0 = { f2b(x[t][0]), f2b(x[t][1]), f2b(x[t][2]), f2b(x[t][3]) };
    ushort4 c1 = { f2b(x[t][4]), f2b(x[t][5]), f2b(x[t][6]), f2b(x[t][7]) };
    u16* q = tib + ((size_t)t * BB + gw) * DIM + d0;
    *(ushort4*)q = c0; *(ushort4*)(q + 4) = c1;
  }
  {
    ushort4 c0 = { f2b(m[0]), f2b(m[1]), f2b(m[2]), f2b(m[3]) };
    ushort4 c1 = { f2b(m[4]), f2b(m[5]), f2b(m[6]), f2b(m[7]) };
    u16* q = xsb + (size_t)gw * DIM + d0;
    *(ushort4*)q = c0; *(ushort4*)(q + 4) = c1;
  }
#pragma unroll
  for (int t = 0; t < 4; t++) {
    const float* wp = qwkb + (size_t)t * DIM + d0;
    float4 w0 = *(const float4*)wp, w1 = *(const float4*)(wp + 4);
    float s = x[t][0]*w0.x + x[t][1]*w0.y + x[t][2]*w0.z + x[t][3]*w0.w
            + x[t][4]*w1.x + x[t][5]*w1.y + x[t][6]*w1.z + x[t][7]*w1.w;
    s = wsum(s);
    if (lane == 0) sbias[(size_t)t * BB + gw] = s + kbqb[t];
  }
}

// ------------- batched transpose+cast: (G,R,C) f32 -> (G,C,R) bf16 -----------
__global__ __launch_bounds__(256) void k_tcast(const float* __restrict__ in,
                                               u16* __restrict__ out,
                                               int R, int C) {
  __shared__ float tile[32][33];
  size_t gb = (size_t)blockIdx.z * R * C;
  in += gb; out += gb;
  int c0 = blockIdx.x * 32, r0 = blockIdx.y * 32;
  int tx = threadIdx.x & 31, ty = threadIdx.x >> 5;
#pragma unroll
  for (int j = 0; j < 4; j++)
    tile[ty + j * 8][tx] = in[(size_t)(r0 + ty + j * 8) * C + c0 + tx];
  __syncthreads();
#pragma unroll
  for (int j = 0; j < 4; j++)
    out[(size_t)(c0 + ty + j * 8) * R + r0 + tx] = f2b(tile[tx][ty + j * 8]);
}

// ---------------- plain cast f32 -> bf16 -------------------------------------
__global__ __launch_bounds__(256) void k_cast(const float* __restrict__ in,
                                              u16* __restrict__ out) {
  size_t i = ((size_t)blockIdx.x * 256 + threadIdx.x) * 4;
  float4 v = *(const float4*)(in + i);
  ushort4 b = { f2b(v.x), f2b(v.y), f2b(v.z), f2b(v.w) };
  *(ushort4*)(out + i) = b;
}

// --------------- small bias-vector precomputes -------------------------------
__global__ __launch_bounds__(256) void k_biasvec(const float* __restrict__ qw,
                                                 const float* __restrict__ kb,
                                                 const float* __restrict__ kw,
                                                 const float* __restrict__ qb,
                                                 float* __restrict__ qwkb,
                                                 float* __restrict__ kwqb,
                                                 float* __restrict__ kbqb) {
  int gw = (blockIdx.x * 256 + threadIdx.x) >> 6;
  int lane = threadIdx.x & 63;
  if (gw < 2048) {
    int t = gw >> 9, c = gw & 511;
    const float* row = qw + ((size_t)t * DIM + c) * DIM;
    const float* v = kb + (size_t)t * DIM;
    float s = 0;
#pragma unroll
    for (int j = 0; j < 8; j++) s += row[lane * 8 + j] * v[lane * 8 + j];
    s = wsum(s);
    if (lane == 0) qwkb[(size_t)t * DIM + c] = s;
  } else if (gw < 4096) {
    int t = (gw - 2048) >> 9, d = gw & 511;
    const float* row = kw + ((size_t)t * DIM + d) * DIM;
    const float* v = qb + (size_t)t * DIM;
    float s = 0;
#pragma unroll
    for (int j = 0; j < 8; j++) s += row[lane * 8 + j] * v[lane * 8 + j];
    s = wsum(s);
    if (lane == 0) kwqb[(size_t)t * DIM + d] = s;
  } else if (gw < 4100) {
    int t = gw - 4096;
    const float* a = kb + (size_t)t * DIM;
    const float* c = qb + (size_t)t * DIM;
    float s = 0;
#pragma unroll
    for (int j = 0; j < 8; j++) s += a[lane * 8 + j] * c[lane * 8 + j];
    s = wsum(s);
    if (lane == 0) kbqb[t] = s;
  }
}

// ---------------- 128x128 bf16 MFMA GEMM mainloop (NT) -----------------------
__device__ __forceinline__ void gemm128(const u16* __restrict__ Ag, int lda,
                                        const u16* __restrict__ Bg, int ldb,
                                        int K, f32x4 acc[4][4]) {
  __shared__ __align__(16) u16 lA[4096];
  __shared__ __align__(16) u16 lB[4096];
  const int tid = threadIdx.x;
  const int lane = tid & 63;
  const int wave = tid >> 6;
  const int wm = wave >> 1, wn = wave & 1;
  const u16* a0 = Ag + (size_t)(tid >> 2) * lda + (tid & 3) * 8;
  const u16* a1 = a0 + (size_t)64 * lda;
  const u16* b0 = Bg + (size_t)(tid >> 2) * ldb + (tid & 3) * 8;
  const u16* b1 = b0 + (size_t)64 * ldb;
  u16* la0 = &lA[tid * 8];
  u16* la1 = &lA[2048 + tid * 8];
  u16* lb0 = &lB[tid * 8];
  u16* lb1 = &lB[2048 + tid * 8];
  const int ao = (wm * 64 + (lane & 15)) * 32 + (lane >> 4) * 8;
  const int bo = (wn * 64 + (lane & 15)) * 32 + (lane >> 4) * 8;
  for (int k0 = 0; k0 < K; k0 += 32) {
    __syncthreads();
    GLOAD16(a0 + k0, la0);
    GLOAD16(a1 + k0, la1);
    GLOAD16(b0 + k0, lb0);
    GLOAD16(b1 + k0, lb1);
    __syncthreads();
    short8 af[4], bf[4];
#pragma unroll
    for (int i = 0; i < 4; i++) {
      af[i] = *(const short8*)&lA[ao + i * 512];
      bf[i] = *(const short8*)&lB[bo + i * 512];
    }
#pragma unroll
    for (int mi = 0; mi < 4; mi++)
#pragma unroll
      for (int ni = 0; ni < 4; ni++)
        acc[mi][ni] = __builtin_amdgcn_mfma_f32_16x16x32_bf16(af[mi], bf[ni],
                                                              acc[mi][ni], 0, 0, 0);
  }
}

// ---------------- expert up-GEMM: h = gelu(x@W1 + b1), bf16 out --------------
__global__ __launch_bounds__(256) void k_gemm_up(const u16* __restrict__ xsb,
                                                 const u16* __restrict__ tib,
                                                 const u16* __restrict__ w1t,
                                                 const float* __restrict__ sb1,
                                                 const float* __restrict__ tb1,
                                                 u16* __restrict__ hbuf,
                                                 int row0, int SR) {
  int ge = blockIdx.z;
  const u16* A;
  const float* bias;
  if (ge < 4) { A = xsb; bias = sb1 + (size_t)ge * HDIM; }
  else {
    int te = ge - 4;
    A = tib + (size_t)(te >> 2) * BD;
    bias = tb1 + (size_t)te * HDIM;
  }
  A += (size_t)row0 * DIM;
  const u16* W = w1t + (size_t)ge * ((size_t)HDIM * DIM);
  int m0 = blockIdx.y * 128, n0 = blockIdx.x * 128;
  f32x4 acc[4][4] = {};
  gemm128(A + (size_t)m0 * DIM, DIM, W + (size_t)n0 * DIM, DIM, DIM, acc);
  u16* out = hbuf + (size_t)ge * ((size_t)SR * HDIM);
  const int lane = threadIdx.x & 63, wave = threadIdx.x >> 6;
  const int rbase = m0 + (wave >> 1) * 64 + (lane >> 4) * 4;
  const int cbase = n0 + (wave & 1) * 64 + (lane & 15);
#pragma unroll
  for (int mi = 0; mi < 4; mi++)
#pragma unroll
    for (int ni = 0; ni < 4; ni++)
#pragma unroll
      for (int r = 0; r < 4; r++) {
        int row = rbase + mi * 16 + r;
        int col = cbase + ni * 16;
        float v = acc[mi][ni][r] + bias[col];
        out[(size_t)row * HDIM + col] = f2b(fgelu(v));
      }
}

// ---- fused down-GEMM + bias + residual + LayerNorm -> stacked ---------------
// 64 x 512 tile, K=HDIM, BK=32 double-buffered, XOR bank swizzle, setprio.
__global__ __launch_bounds__(512) void k_down_ln(const u16* __restrict__ hbuf,
                                                 const u16* __restrict__ w2t,
                                                 const float* __restrict__ sb2,
                                                 const float* __restrict__ tb2,
                                                 const u16* __restrict__ xsb,
                                                 const u16* __restrict__ tib,
                                                 const float* __restrict__ sg,
                                                 const float* __restrict__ sbt,
                                                 const float* __restrict__ tg,
                                                 const float* __restrict__ tbt,
                                                 float* __restrict__ stacked,
                                                 int row0, int SR) {
  __shared__ __align__(16) u16 lA[2][2048];    // 2 x (64 x 32)
  __shared__ __align__(16) u16 lB[2][16384];   // 2 x (512 x 32)
  __shared__ float partS[256], partQ[256];
  const int ge = blockIdx.z;
  const int tid = threadIdx.x;
  const int lane = tid & 63, wave = tid >> 6;
  const int wm = wave >> 2, wn = wave & 3;
  const int rl = lane & 15;
  const int hs = ((lane >> 4) ^ ((rl >> 1) & 3)) * 8;   // swizzled read chunk
  const int m0 = blockIdx.x * 64;
  const u16* Ag = hbuf + (size_t)ge * ((size_t)SR * HDIM) + (size_t)m0 * HDIM;
  const u16* Bg = w2t + (size_t)ge * ((size_t)DIM * HDIM);
  const int gc = ((tid & 3) ^ ((tid >> 3) & 3)) * 8;    // pre-swizzled src chunk
  const u16* aS = Ag + (size_t)(tid >> 2) * HDIM + gc;
  const u16* bS = Bg + (size_t)(tid >> 2) * HDIM + gc;
  f32x4 acc[2][8] = {};
  // prologue: stage k=0 into buf 0
  if (tid < 256) GLOAD16(aS, &lA[0][tid * 8]);
#pragma unroll
  for (int j = 0; j < 4; j++)
    GLOAD16(bS + (size_t)j * 128 * HDIM, &lB[0][(tid + j * 512) * 8]);
  __syncthreads();
  for (int k = 0; k < 32; ++k) {
    const int cur = k & 1;
    if (k < 31) {                       // issue next-tile loads first (overlap)
      const int nk = (k + 1) * 32;
      if (tid < 256) GLOAD16(aS + nk, &lA[cur ^ 1][tid * 8]);
#pragma unroll
      for (int j = 0; j < 4; j++)
        GLOAD16(bS + (size_t)j * 128 * HDIM + nk, &lB[cur ^ 1][(tid + j * 512) * 8]);
    }
    short8 af[2], bf[8];
#pragma unroll
    for (int mf = 0; mf < 2; mf++)
      af[mf] = *(const short8*)&lA[cur][(wm * 32 + mf * 16 + rl) * 32 + hs];
#pragma unroll
    for (int nf = 0; nf < 8; nf++)
      bf[nf] = *(const short8*)&lB[cur][(wn * 128 + nf * 16 + rl) * 32 + hs];
    __builtin_amdgcn_s_setprio(1);
#pragma unroll
    for (int mf = 0; mf < 2; mf++)
#pragma unroll
      for (int nf = 0; nf < 8; nf++)
        acc[mf][nf] = __builtin_amdgcn_mfma_f32_16x16x32_bf16(bf[nf], af[mf],
                                                              acc[mf][nf], 0, 0, 0);
    __builtin_amdgcn_s_setprio(0);
    __syncthreads();                    // drains vmcnt: staged tile ready
  }
  // ---- epilogue: bias + residual (bf16), row LN over 512 cols ----
  const float* bias; const u16* resb; const float* gp; const float* bp;
  int te = ge - 4;
  if (ge < 4) {
    bias = sb2 + (size_t)ge * DIM; resb = xsb;
    gp = sg + (size_t)ge * DIM;    bp = sbt + (size_t)ge * DIM;
  } else {
    bias = tb2 + (size_t)te * DIM; resb = tib + (size_t)(te >> 2) * BD;
    gp = tg + (size_t)te * DIM;    bp = tbt + (size_t)te * DIM;
  }
  const int c4 = (lane >> 4) * 4;
  float sv[2], qv[2];
#pragma unroll
  for (int mf = 0; mf < 2; mf++) {
    int grow = row0 + m0 + wm * 32 + mf * 16 + rl;
    float s = 0, q = 0;
#pragma unroll
    for (int nf = 0; nf < 8; nf++) {
      int n = wn * 128 + nf * 16 + c4;
      float4 bb = *(const float4*)(bias + n);
      ushort4 rr = *(const ushort4*)(resb + (size_t)grow * DIM + n);
      float rf[4] = { b2f(rr.x), b2f(rr.y), b2f(rr.z), b2f(rr.w) };
#pragma unroll
      for (int r = 0; r < 4; r++) {
        float v = acc[mf][nf][r] + ((const float*)&bb)[r] + rf[r];
        acc[mf][nf][r] = v; s += v; q += v * v;
      }
    }
    s += __shfl_xor(s, 16); s += __shfl_xor(s, 32);
    q += __shfl_xor(q, 16); q += __shfl_xor(q, 32);
    sv[mf] = s; qv[mf] = q;
  }
  if (lane < 16) {
#pragma unroll
    for (int mf = 0; mf < 2; mf++) {
      partS[wn * 64 + wm * 32 + mf * 16 + lane] = sv[mf];
      partQ[wn * 64 + wm * 32 + mf * 16 + lane] = qv[mf];
    }
  }
  __syncthreads();
  float mu[2], rsg[2];
#pragma unroll
  for (int mf = 0; mf < 2; mf++) {
    int ridx = wm * 32 + mf * 16 + rl;
    float S = partS[ridx] + partS[64 + ridx] + partS[128 + ridx] + partS[192 + ridx];
    float Q = partQ[ridx] + partQ[64 + ridx] + partQ[128 + ridx] + partQ[192 + ridx];
    float m = S * (1.0f / DIM);
    float var = Q * (1.0f / DIM) - m * m;
    mu[mf] = m; rsg[mf] = rsqrtf(var + 1e-5f);
  }
#pragma unroll
  for (int nf = 0; nf < 8; nf++) {
    int n = wn * 128 + nf * 16 + c4;
    float4 gg = *(const float4*)(gp + n);
    float4 bb = *(const float4*)(bp + n);
#pragma unroll
    for (int mf = 0; mf < 2; mf++) {
      int grow = row0 + m0 + wm * 32 + mf * 16 + rl;
      float4 y;
#pragma unroll
      for (int r = 0; r < 4; r++)
        ((float*)&y)[r] = (acc[mf][nf][r] - mu[mf]) * rsg[mf] *
                          ((const float*)&gg)[r] + ((const float*)&bb)[r];
      if (ge < 4) {
#pragma unroll
        for (int t = 0; t < 4; t++)
          *(float4*)(stacked + (((size_t)t * 8 + ge) * BB + grow) * DIM + n) = y;
      } else {
        *(float4*)(stacked + (((size_t)(te >> 2) * 8 + 4 + (te & 3)) * BB + grow) * DIM + n) = y;
      }
    }
  }
}

// ---------------- MT[t] = kw[t] @ qw[t]^T  (bf16 out) ------------------------
__global__ __launch_bounds__(256) void k_gemm_mt(const u16* __restrict__ kwb,
                                                 const u16* __restrict__ qwb,
                                                 u16* __restrict__ mt) {
  int t = blockIdx.z;
  int m0 = blockIdx.y * 128, n0 = blockIdx.x * 128;
  f32x4 acc[4][4] = {};
  gemm128(kwb + (size_t)t * D2 + (size_t)m0 * DIM, DIM,
          qwb + (size_t)t * D2 + (size_t)n0 * DIM, DIM, DIM, acc);
  const int lane = threadIdx.x & 63, wave = threadIdx.x >> 6;
  const int rbase = m0 + (wave >> 1) * 64 + (lane >> 4) * 4;
  const int cbase = n0 + (wave & 1) * 64 + (lane & 15);
#pragma unroll
  for (int mi = 0; mi < 4; mi++)
#pragma unroll
    for (int ni = 0; ni < 4; ni++)
#pragma unroll
      for (int r = 0; r < 4; r++)
        mt[(size_t)t * D2 + (size_t)(rbase + mi * 16 + r) * DIM + cbase + ni * 16] =
            f2b(acc[mi][ni][r]);
}

// ------------- qkb[t] = bf16(x[t] @ MT[t]^T + kwqb[t]) -----------------------
__global__ __launch_bounds__(256) void k_gemm_qk(const u16* __restrict__ tib,
                                                 const u16* __restrict__ mt,
                                                 const float* __restrict__ kwqb,
                                                 u16* __restrict__ qkb) {
  int t = blockIdx.z;
  int m0 = blockIdx.y * 128, n0 = blockIdx.x * 128;
  f32x4 acc[4][4] = {};
  gemm128(tib + (size_t)t * BD + (size_t)m0 * DIM, DIM,
          mt + (size_t)t * D2 + (size_t)n0 * DIM, DIM, DIM, acc);
  const int lane = threadIdx.x & 63, wave = threadIdx.x >> 6;
  const int rbase = m0 + (wave >> 1) * 64 + (lane >> 4) * 4;
  const int cbase = n0 + (wave & 1) * 64 + (lane & 15);
#pragma unroll
  for (int mi = 0; mi < 4; mi++)
#pragma unroll
    for (int ni = 0; ni < 4; ni++)
#pragma unroll
      for (int r = 0; r < 4; r++) {
        int col = cbase + ni * 16;
        qkb[(size_t)t * BD + (size_t)(rbase + mi * 16 + r) * DIM + col] =
            f2b(acc[mi][ni][r] + kwqb[(size_t)t * DIM + col]);
      }
}

// ------------ fused scores + softmax + gating (one wave per (t,b)) -----------
__global__ __launch_bounds__(256) void k_score(const float* __restrict__ stk,
                                               const u16* __restrict__ qkb,
                                               const float* __restrict__ sbias,
                                               float* __restrict__ gated,
                                               float* __restrict__ wout) {
  int gw = (blockIdx.x * 256 + threadIdx.x) >> 6;
  int lane = threadIdx.x & 63;
  int b = gw & (BB - 1), t = gw >> 12;
  int d0 = lane * 8;
  size_t rowoff = ((size_t)t * BB + b) * DIM + d0;
  float qr[8];
  {
    ushort4 q0 = *(const ushort4*)(qkb + rowoff);
    ushort4 q1 = *(const ushort4*)(qkb + rowoff + 4);
    qr[0] = b2f(q0.x); qr[1] = b2f(q0.y); qr[2] = b2f(q0.z); qr[3] = b2f(q0.w);
    qr[4] = b2f(q1.x); qr[5] = b2f(q1.y); qr[6] = b2f(q1.z); qr[7] = b2f(q1.w);
  }
  float stv[8][8];
  float dots[8];
#pragma unroll
  for (int n = 0; n < 8; n++) {
    const float* sr = stk + (((size_t)t * 8 + n) * BB + b) * DIM + d0;
    *(float4*)&stv[n][0] = *(const float4*)(sr);
    *(float4*)&stv[n][4] = *(const float4*)(sr + 4);
    float s = 0;
#pragma unroll
    for (int j = 0; j < 8; j++) s += stv[n][j] * qr[j];
    dots[n] = wsum(s);
  }
  float sb = sbias[(size_t)t * BB + b];
  const float inv = 0.04419417382415922f;  // 1/sqrt(512)
  float sc[8], e[8];
  float mx = -1e30f;
#pragma unroll
  for (int n = 0; n < 8; n++) { sc[n] = (dots[n] + sb) * inv; mx = fmaxf(mx, sc[n]); }
  float den = 0;
#pragma unroll
  for (int n = 0; n < 8; n++) { e[n] = expf(sc[n] - mx); den += e[n]; }
  float rden = 1.0f / den;
  float wv[8];
#pragma unroll
  for (int n = 0; n < 8; n++) wv[n] = e[n] * rden;
  float wsel = 0;
#pragma unroll
  for (int n = 0; n < 8; n++) wsel = (lane == n) ? wv[n] : wsel;
  if (lane < 8) wout[((size_t)t * BB + b) * 8 + lane] = wsel;
  float g[8];
#pragma unroll
  for (int j = 0; j < 8; j++) {
    float s = 0;
#pragma unroll
    for (int n = 0; n < 8; n++) s += wv[n] * stv[n][j];
    g[j] = s;
  }
  float* go = gated + rowoff;
  *(float4*)(go) = *(float4*)&g[0];
  *(float4*)(go + 4) = *(float4*)&g[4];
}

// ============================ host launcher ==================================
extern "C" void kernel_launch(void* const* d_in, const int* in_sizes, int n_in,
                              void* d_out, int out_size, void* d_ws, size_t ws_size,
                              hipStream_t stream) {
  const float* ti  = (const float*)d_in[0];
  const float* sw1 = (const float*)d_in[1];
  const float* sb1 = (const float*)d_in[2];
  const float* sw2 = (const float*)d_in[3];
  const float* sb2 = (const float*)d_in[4];
  const float* sg  = (const float*)d_in[5];
  const float* sbt = (const float*)d_in[6];
  const float* tw1 = (const float*)d_in[7];
  const float* tb1 = (const float*)d_in[8];
  const float* tw2 = (const float*)d_in[9];
  const float* tb2 = (const float*)d_in[10];
  const float* tg  = (const float*)d_in[11];
  const float* tbt = (const float*)d_in[12];
  const float* qw  = (const float*)d_in[13];
  const float* qb  = (const float*)d_in[14];
  const float* kw  = (const float*)d_in[15];
  const float* kb  = (const float*)d_in[16];

  float* out = (float*)d_out;
  float* gated   = out;                                   // T*B*D
  float* weights = out + (size_t)TT * BB * DIM;           // T*B*8
  float* stacked = weights + (size_t)TT * BB * 8;         // T*8*B*D

  char* ws = (char*)d_ws;
  u16*   tib   = (u16*)(ws);                    // 16,777,216
  u16*   xsb   = (u16*)(ws + 16777216);         //  4,194,304
  u16*   w1t   = (u16*)(ws + 20971520);         // 20,971,520
  u16*   w2t   = (u16*)(ws + 41943040);         // 20,971,520
  u16*   qwb   = (u16*)(ws + 62914560);         //  2,097,152
  u16*   kwb   = (u16*)(ws + 65011712);         //  2,097,152
  u16*   mt    = (u16*)(ws + 67108864);         //  2,097,152
  float* sbias = (float*)(ws + 69206016);       //     65,536
  float* qwkb  = (float*)(ws + 69271552);       //      8,192
  float* kwqb  = (float*)(ws + 69279744);       //      8,192
  float* kbqb  = (float*)(ws + 69287936);       //      1,024
  u16*   hbuf  = (u16*)(ws + 69288960);         // SR*HDIM*2*20
  u16*   qkb   = (u16*)(ws + 69288960);         // aliased: used after expert loop

  const size_t hoff = 69288960;
  int SR = (ws_size >= hoff + (size_t)20 * 1024 * HDIM * 2) ? 1024 : 512;

  // weight / gate preprocessing
  k_tcast<<<dim3(32, 16, 4), 256, 0, stream>>>(sw1, w1t, DIM, HDIM);
  k_tcast<<<dim3(32, 16, 16), 256, 0, stream>>>(tw1, w1t + (size_t)4 * HDIM * DIM, DIM, HDIM);
  k_tcast<<<dim3(16, 32, 4), 256, 0, stream>>>(sw2, w2t, HDIM, DIM);
  k_tcast<<<dim3(16, 32, 16), 256, 0, stream>>>(tw2, w2t + (size_t)4 * DIM * HDIM, HDIM, DIM);
  k_cast<<<1024, 256, 0, stream>>>(qw, qwb);
  k_cast<<<1024, 256, 0, stream>>>(kw, kwb);
  k_biasvec<<<1025, 256, 0, stream>>>(qw, kb, kw, qb, qwkb, kwqb, kbqb);
  k_prep<<<1024, 256, 0, stream>>>(ti, qwkb, kbqb, tib, xsb, sbias);
  k_gemm_mt<<<dim3(4, 4, 4), 256, 0, stream>>>(kwb, qwb, mt);

  // expert FFNs, striped over rows so all 20 experts fill one dispatch
  for (int row0 = 0; row0 < BB; row0 += SR) {
    k_gemm_up<<<dim3(8, SR / 128, NEXP), 256, 0, stream>>>(xsb, tib, w1t, sb1, tb1,
                                                           hbuf, row0, SR);
    k_down_ln<<<dim3(SR / 64, 1, NEXP), 512, 0, stream>>>(hbuf, w2t, sb2, tb2,
                                                          xsb, tib, sg, sbt, tg, tbt,
                                                          stacked, row0, SR);
  }

  k_gemm_qk<<<dim3(4, 32, 4), 256, 0, stream>>>(tib, mt, kwqb, qkb);
  k_score<<<4096, 256, 0, stream>>>(stacked, qkb, sbias, gated, weights);
}

// Round 4
// 525.394 us; speedup vs baseline: 1.2749x; 1.2749x over previous
//
#include <hip/hip_runtime.h>
#include <math.h>

typedef unsigned short u16;
typedef short short8 __attribute__((ext_vector_type(8)));
typedef float f32x4 __attribute__((ext_vector_type(4)));

#define TT 4
#define BB 4096
#define DIM 512
#define HDIM 1024
#define BD (BB*DIM)      // 2097152
#define BH (BB*HDIM)     // 4194304
#define D2 (DIM*DIM)     // 262144
#define NEXP 20

#define GLOAD16(gp, lp) __builtin_amdgcn_global_load_lds( \
    (__attribute__((address_space(1))) void*)(void*)(gp), \
    (__attribute__((address_space(3))) void*)(void*)(lp), 16, 0, 0)

__device__ __forceinline__ u16 f2b(float f) {
  union { float f; unsigned u; } x; x.f = f;
  unsigned r = x.u + 0x7FFFu + ((x.u >> 16) & 1u);
  return (u16)(r >> 16);
}
__device__ __forceinline__ float b2f(u16 v) {
  union { unsigned u; float f; } x; x.u = ((unsigned)v) << 16; return x.f;
}

__device__ __forceinline__ float wsum(float v) {
#pragma unroll
  for (int o = 32; o > 0; o >>= 1) v += __shfl_xor(v, o);
  return v;
}

// fast exact-enough GELU
__device__ __forceinline__ float fgelu(float v) {
  float u = 1.5957691216057308f * v * (1.0f + 0.044715f * v * v);
  return v / (1.0f + __expf(-u));
}

// ------ prep: one wave per row b: mean, bf16 casts, score-bias sbias --------
__global__ __launch_bounds__(256) void k_prep(const float* __restrict__ ti,
                                              const float* __restrict__ qwkb,
                                              const float* __restrict__ kbqb,
                                              u16* __restrict__ tib,
                                              u16* __restrict__ xsb,
                                              float* __restrict__ sbias) {
  int gw = (blockIdx.x * 256 + threadIdx.x) >> 6;   // row b
  int lane = threadIdx.x & 63;
  int d0 = lane * 8;
  float x[4][8];
#pragma unroll
  for (int t = 0; t < 4; t++) {
    const float* p = ti + ((size_t)t * BB + gw) * DIM + d0;
    *(float4*)&x[t][0] = *(const float4*)p;
    *(float4*)&x[t][4] = *(const float4*)(p + 4);
  }
  float m[8];
#pragma unroll
  for (int j = 0; j < 8; j++)
    m[j] = (x[0][j] + x[1][j] + x[2][j] + x[3][j]) * 0.25f;
#pragma unroll
  for (int t = 0; t < 4; t++) {
    ushort4 c0 = { f2b(x[t][0]), f2b(x[t][1]), f2b(x[t][2]), f2b(x[t][3]) };
    ushort4 c1 = { f2b(x[t][4]), f2b(x[t][5]), f2b(x[t][6]), f2b(x[t][7]) };
    u16* q = tib + ((size_t)t * BB + gw) * DIM + d0;
    *(ushort4*)q = c0; *(ushort4*)(q + 4) = c1;
  }
  {
    ushort4 c0 = { f2b(m[0]), f2b(m[1]), f2b(m[2]), f2b(m[3]) };
    ushort4 c1 = { f2b(m[4]), f2b(m[5]), f2b(m[6]), f2b(m[7]) };
    u16* q = xsb + (size_t)gw * DIM + d0;
    *(ushort4*)q = c0; *(ushort4*)(q + 4) = c1;
  }
#pragma unroll
  for (int t = 0; t < 4; t++) {
    const float* wp = qwkb + (size_t)t * DIM + d0;
    float4 w0 = *(const float4*)wp, w1 = *(const float4*)(wp + 4);
    float s = x[t][0]*w0.x + x[t][1]*w0.y + x[t][2]*w0.z + x[t][3]*w0.w
            + x[t][4]*w1.x + x[t][5]*w1.y + x[t][6]*w1.z + x[t][7]*w1.w;
    s = wsum(s);
    if (lane == 0) sbias[(size_t)t * BB + gw] = s + kbqb[t];
  }
}

// ------------- batched transpose+cast: (G,R,C) f32 -> (G,C,R) bf16 -----------
__global__ __launch_bounds__(256) void k_tcast(const float* __restrict__ in,
                                               u16* __restrict__ out,
                                               int R, int C) {
  __shared__ float tile[32][33];
  size_t gb = (size_t)blockIdx.z * R * C;
  in += gb; out += gb;
  int c0 = blockIdx.x * 32, r0 = blockIdx.y * 32;
  int tx = threadIdx.x & 31, ty = threadIdx.x >> 5;
#pragma unroll
  for (int j = 0; j < 4; j++)
    tile[ty + j * 8][tx] = in[(size_t)(r0 + ty + j * 8) * C + c0 + tx];
  __syncthreads();
#pragma unroll
  for (int j = 0; j < 4; j++)
    out[(size_t)(c0 + ty + j * 8) * R + r0 + tx] = f2b(tile[tx][ty + j * 8]);
}

// ---------------- plain cast f32 -> bf16 -------------------------------------
__global__ __launch_bounds__(256) void k_cast(const float* __restrict__ in,
                                              u16* __restrict__ out) {
  size_t i = ((size_t)blockIdx.x * 256 + threadIdx.x) * 4;
  float4 v = *(const float4*)(in + i);
  ushort4 b = { f2b(v.x), f2b(v.y), f2b(v.z), f2b(v.w) };
  *(ushort4*)(out + i) = b;
}

// --------------- small bias-vector precomputes -------------------------------
__global__ __launch_bounds__(256) void k_biasvec(const float* __restrict__ qw,
                                                 const float* __restrict__ kb,
                                                 const float* __restrict__ kw,
                                                 const float* __restrict__ qb,
                                                 float* __restrict__ qwkb,
                                                 float* __restrict__ kwqb,
                                                 float* __restrict__ kbqb) {
  int gw = (blockIdx.x * 256 + threadIdx.x) >> 6;
  int lane = threadIdx.x & 63;
  if (gw < 2048) {
    int t = gw >> 9, c = gw & 511;
    const float* row = qw + ((size_t)t * DIM + c) * DIM;
    const float* v = kb + (size_t)t * DIM;
    float s = 0;
#pragma unroll
    for (int j = 0; j < 8; j++) s += row[lane * 8 + j] * v[lane * 8 + j];
    s = wsum(s);
    if (lane == 0) qwkb[(size_t)t * DIM + c] = s;
  } else if (gw < 4096) {
    int t = (gw - 2048) >> 9, d = gw & 511;
    const float* row = kw + ((size_t)t * DIM + d) * DIM;
    const float* v = qb + (size_t)t * DIM;
    float s = 0;
#pragma unroll
    for (int j = 0; j < 8; j++) s += row[lane * 8 + j] * v[lane * 8 + j];
    s = wsum(s);
    if (lane == 0) kwqb[(size_t)t * DIM + d] = s;
  } else if (gw < 4100) {
    int t = gw - 4096;
    const float* a = kb + (size_t)t * DIM;
    const float* c = qb + (size_t)t * DIM;
    float s = 0;
#pragma unroll
    for (int j = 0; j < 8; j++) s += a[lane * 8 + j] * c[lane * 8 + j];
    s = wsum(s);
    if (lane == 0) kbqb[t] = s;
  }
}

// ---------------- 128x128 bf16 MFMA GEMM mainloop (NT) -----------------------
__device__ __forceinline__ void gemm128(const u16* __restrict__ Ag, int lda,
                                        const u16* __restrict__ Bg, int ldb,
                                        int K, f32x4 acc[4][4]) {
  __shared__ __align__(16) u16 lA[4096];
  __shared__ __align__(16) u16 lB[4096];
  const int tid = threadIdx.x;
  const int lane = tid & 63;
  const int wave = tid >> 6;
  const int wm = wave >> 1, wn = wave & 1;
  const u16* a0 = Ag + (size_t)(tid >> 2) * lda + (tid & 3) * 8;
  const u16* a1 = a0 + (size_t)64 * lda;
  const u16* b0 = Bg + (size_t)(tid >> 2) * ldb + (tid & 3) * 8;
  const u16* b1 = b0 + (size_t)64 * ldb;
  u16* la0 = &lA[tid * 8];
  u16* la1 = &lA[2048 + tid * 8];
  u16* lb0 = &lB[tid * 8];
  u16* lb1 = &lB[2048 + tid * 8];
  const int ao = (wm * 64 + (lane & 15)) * 32 + (lane >> 4) * 8;
  const int bo = (wn * 64 + (lane & 15)) * 32 + (lane >> 4) * 8;
  for (int k0 = 0; k0 < K; k0 += 32) {
    __syncthreads();
    GLOAD16(a0 + k0, la0);
    GLOAD16(a1 + k0, la1);
    GLOAD16(b0 + k0, lb0);
    GLOAD16(b1 + k0, lb1);
    __syncthreads();
    short8 af[4], bf[4];
#pragma unroll
    for (int i = 0; i < 4; i++) {
      af[i] = *(const short8*)&lA[ao + i * 512];
      bf[i] = *(const short8*)&lB[bo + i * 512];
    }
#pragma unroll
    for (int mi = 0; mi < 4; mi++)
#pragma unroll
      for (int ni = 0; ni < 4; ni++)
        acc[mi][ni] = __builtin_amdgcn_mfma_f32_16x16x32_bf16(af[mi], bf[ni],
                                                              acc[mi][ni], 0, 0, 0);
  }
}

// ---------------- expert up-GEMM: h = gelu(x@W1 + b1), bf16 out --------------
__global__ __launch_bounds__(256) void k_gemm_up(const u16* __restrict__ xsb,
                                                 const u16* __restrict__ tib,
                                                 const u16* __restrict__ w1t,
                                                 const float* __restrict__ sb1,
                                                 const float* __restrict__ tb1,
                                                 u16* __restrict__ hbuf,
                                                 int row0, int SR) {
  int ge = blockIdx.z;
  const u16* A;
  const float* bias;
  if (ge < 4) { A = xsb; bias = sb1 + (size_t)ge * HDIM; }
  else {
    int te = ge - 4;
    A = tib + (size_t)(te >> 2) * BD;
    bias = tb1 + (size_t)te * HDIM;
  }
  A += (size_t)row0 * DIM;
  const u16* W = w1t + (size_t)ge * ((size_t)HDIM * DIM);
  int m0 = blockIdx.y * 128, n0 = blockIdx.x * 128;
  f32x4 acc[4][4] = {};
  gemm128(A + (size_t)m0 * DIM, DIM, W + (size_t)n0 * DIM, DIM, DIM, acc);
  u16* out = hbuf + (size_t)ge * ((size_t)SR * HDIM);
  const int lane = threadIdx.x & 63, wave = threadIdx.x >> 6;
  const int rbase = m0 + (wave >> 1) * 64 + (lane >> 4) * 4;
  const int cbase = n0 + (wave & 1) * 64 + (lane & 15);
#pragma unroll
  for (int mi = 0; mi < 4; mi++)
#pragma unroll
    for (int ni = 0; ni < 4; ni++)
#pragma unroll
      for (int r = 0; r < 4; r++) {
        int row = rbase + mi * 16 + r;
        int col = cbase + ni * 16;
        float v = acc[mi][ni][r] + bias[col];
        out[(size_t)row * HDIM + col] = f2b(fgelu(v));
      }
}

// ---- fused down-GEMM + bias + residual + LayerNorm -> stacked ---------------
// 64 x 512 tile, K=HDIM, single-buffer BK=32, XOR bank swizzle (both sides).
__global__ __launch_bounds__(512, 4) void k_down_ln(const u16* __restrict__ hbuf,
                                                 const u16* __restrict__ w2t,
                                                 const float* __restrict__ sb2,
                                                 const float* __restrict__ tb2,
                                                 const u16* __restrict__ xsb,
                                                 const u16* __restrict__ tib,
                                                 const float* __restrict__ sg,
                                                 const float* __restrict__ sbt,
                                                 const float* __restrict__ tg,
                                                 const float* __restrict__ tbt,
                                                 float* __restrict__ stacked,
                                                 int row0, int SR) {
  __shared__ __align__(16) u16 lA[2048];    // 64 x 32
  __shared__ __align__(16) u16 lB[16384];   // 512 x 32
  __shared__ float partS[256], partQ[256];
  const int ge = blockIdx.z;
  const int tid = threadIdx.x;
  const int lane = tid & 63, wave = tid >> 6;
  const int wm = wave >> 2, wn = wave & 3;
  const int rl = lane & 15;
  const int hs = ((lane >> 4) ^ ((rl >> 1) & 3)) * 8;   // swizzled read chunk
  const int m0 = blockIdx.x * 64;
  const u16* Ag = hbuf + (size_t)ge * ((size_t)SR * HDIM) + (size_t)m0 * HDIM;
  const u16* Bg = w2t + (size_t)ge * ((size_t)DIM * HDIM);
  const int gc = ((tid & 3) ^ ((tid >> 3) & 3)) * 8;    // pre-swizzled src chunk
  const u16* aS = Ag + (size_t)(tid >> 2) * HDIM + gc;
  const u16* bS = Bg + (size_t)(tid >> 2) * HDIM + gc;
  f32x4 acc[2][8] = {};
  for (int k0 = 0; k0 < HDIM; k0 += 32) {
    __syncthreads();
    if (tid < 256) GLOAD16(aS + k0, &lA[tid * 8]);
#pragma unroll
    for (int j = 0; j < 4; j++)
      GLOAD16(bS + (size_t)j * 128 * HDIM + k0, &lB[(tid + j * 512) * 8]);
    __syncthreads();
    short8 af[2], bf[8];
#pragma unroll
    for (int mf = 0; mf < 2; mf++)
      af[mf] = *(const short8*)&lA[(wm * 32 + mf * 16 + rl) * 32 + hs];
#pragma unroll
    for (int nf = 0; nf < 8; nf++)
      bf[nf] = *(const short8*)&lB[(wn * 128 + nf * 16 + rl) * 32 + hs];
    __builtin_amdgcn_s_setprio(1);
#pragma unroll
    for (int mf = 0; mf < 2; mf++)
#pragma unroll
      for (int nf = 0; nf < 8; nf++)
        acc[mf][nf] = __builtin_amdgcn_mfma_f32_16x16x32_bf16(bf[nf], af[mf],
                                                              acc[mf][nf], 0, 0, 0);
    __builtin_amdgcn_s_setprio(0);
  }
  // ---- epilogue: bias + residual (bf16), row LN over 512 cols ----
  const float* bias; const u16* resb; const float* gp; const float* bp;
  int te = ge - 4;
  if (ge < 4) {
    bias = sb2 + (size_t)ge * DIM; resb = xsb;
    gp = sg + (size_t)ge * DIM;    bp = sbt + (size_t)ge * DIM;
  } else {
    bias = tb2 + (size_t)te * DIM; resb = tib + (size_t)(te >> 2) * BD;
    gp = tg + (size_t)te * DIM;    bp = tbt + (size_t)te * DIM;
  }
  const int c4 = (lane >> 4) * 4;
  float sv[2], qv[2];
#pragma unroll
  for (int mf = 0; mf < 2; mf++) {
    int grow = row0 + m0 + wm * 32 + mf * 16 + rl;
    float s = 0, q = 0;
#pragma unroll
    for (int nf = 0; nf < 8; nf++) {
      int n = wn * 128 + nf * 16 + c4;
      float4 bb = *(const float4*)(bias + n);
      ushort4 rr = *(const ushort4*)(resb + (size_t)grow * DIM + n);
      float rf[4] = { b2f(rr.x), b2f(rr.y), b2f(rr.z), b2f(rr.w) };
#pragma unroll
      for (int r = 0; r < 4; r++) {
        float v = acc[mf][nf][r] + ((const float*)&bb)[r] + rf[r];
        acc[mf][nf][r] = v; s += v; q += v * v;
      }
    }
    s += __shfl_xor(s, 16); s += __shfl_xor(s, 32);
    q += __shfl_xor(q, 16); q += __shfl_xor(q, 32);
    sv[mf] = s; qv[mf] = q;
  }
  __syncthreads();
  if (lane < 16) {
#pragma unroll
    for (int mf = 0; mf < 2; mf++) {
      partS[wn * 64 + wm * 32 + mf * 16 + lane] = sv[mf];
      partQ[wn * 64 + wm * 32 + mf * 16 + lane] = qv[mf];
    }
  }
  __syncthreads();
  float mu[2], rsg[2];
#pragma unroll
  for (int mf = 0; mf < 2; mf++) {
    int ridx = wm * 32 + mf * 16 + rl;
    float S = partS[ridx] + partS[64 + ridx] + partS[128 + ridx] + partS[192 + ridx];
    float Q = partQ[ridx] + partQ[64 + ridx] + partQ[128 + ridx] + partQ[192 + ridx];
    float m = S * (1.0f / DIM);
    float var = Q * (1.0f / DIM) - m * m;
    mu[mf] = m; rsg[mf] = rsqrtf(var + 1e-5f);
  }
#pragma unroll
  for (int nf = 0; nf < 8; nf++) {
    int n = wn * 128 + nf * 16 + c4;
    float4 gg = *(const float4*)(gp + n);
    float4 bb = *(const float4*)(bp + n);
#pragma unroll
    for (int mf = 0; mf < 2; mf++) {
      int grow = row0 + m0 + wm * 32 + mf * 16 + rl;
      float4 y;
#pragma unroll
      for (int r = 0; r < 4; r++)
        ((float*)&y)[r] = (acc[mf][nf][r] - mu[mf]) * rsg[mf] *
                          ((const float*)&gg)[r] + ((const float*)&bb)[r];
      if (ge < 4) {
#pragma unroll
        for (int t = 0; t < 4; t++)
          *(float4*)(stacked + (((size_t)t * 8 + ge) * BB + grow) * DIM + n) = y;
      } else {
        *(float4*)(stacked + (((size_t)(te >> 2) * 8 + 4 + (te & 3)) * BB + grow) * DIM + n) = y;
      }
    }
  }
}

// ---------------- MT[t] = kw[t] @ qw[t]^T  (bf16 out) ------------------------
__global__ __launch_bounds__(256) void k_gemm_mt(const u16* __restrict__ kwb,
                                                 const u16* __restrict__ qwb,
                                                 u16* __restrict__ mt) {
  int t = blockIdx.z;
  int m0 = blockIdx.y * 128, n0 = blockIdx.x * 128;
  f32x4 acc[4][4] = {};
  gemm128(kwb + (size_t)t * D2 + (size_t)m0 * DIM, DIM,
          qwb + (size_t)t * D2 + (size_t)n0 * DIM, DIM, DIM, acc);
  const int lane = threadIdx.x & 63, wave = threadIdx.x >> 6;
  const int rbase = m0 + (wave >> 1) * 64 + (lane >> 4) * 4;
  const int cbase = n0 + (wave & 1) * 64 + (lane & 15);
#pragma unroll
  for (int mi = 0; mi < 4; mi++)
#pragma unroll
    for (int ni = 0; ni < 4; ni++)
#pragma unroll
      for (int r = 0; r < 4; r++)
        mt[(size_t)t * D2 + (size_t)(rbase + mi * 16 + r) * DIM + cbase + ni * 16] =
            f2b(acc[mi][ni][r]);
}

// ------------- qkb[t] = bf16(x[t] @ MT[t]^T + kwqb[t]) -----------------------
__global__ __launch_bounds__(256) void k_gemm_qk(const u16* __restrict__ tib,
                                                 const u16* __restrict__ mt,
                                                 const float* __restrict__ kwqb,
                                                 u16* __restrict__ qkb) {
  int t = blockIdx.z;
  int m0 = blockIdx.y * 128, n0 = blockIdx.x * 128;
  f32x4 acc[4][4] = {};
  gemm128(tib + (size_t)t * BD + (size_t)m0 * DIM, DIM,
          mt + (size_t)t * D2 + (size_t)n0 * DIM, DIM, DIM, acc);
  const int lane = threadIdx.x & 63, wave = threadIdx.x >> 6;
  const int rbase = m0 + (wave >> 1) * 64 + (lane >> 4) * 4;
  const int cbase = n0 + (wave & 1) * 64 + (lane & 15);
#pragma unroll
  for (int mi = 0; mi < 4; mi++)
#pragma unroll
    for (int ni = 0; ni < 4; ni++)
#pragma unroll
      for (int r = 0; r < 4; r++) {
        int col = cbase + ni * 16;
        qkb[(size_t)t * BD + (size_t)(rbase + mi * 16 + r) * DIM + col] =
            f2b(acc[mi][ni][r] + kwqb[(size_t)t * DIM + col]);
      }
}

// ------------ fused scores + softmax + gating (one wave per (t,b)) -----------
__global__ __launch_bounds__(256) void k_score(const float* __restrict__ stk,
                                               const u16* __restrict__ qkb,
                                               const float* __restrict__ sbias,
                                               float* __restrict__ gated,
                                               float* __restrict__ wout) {
  int gw = (blockIdx.x * 256 + threadIdx.x) >> 6;
  int lane = threadIdx.x & 63;
  int b = gw & (BB - 1), t = gw >> 12;
  int d0 = lane * 8;
  size_t rowoff = ((size_t)t * BB + b) * DIM + d0;
  float qr[8];
  {
    ushort4 q0 = *(const ushort4*)(qkb + rowoff);
    ushort4 q1 = *(const ushort4*)(qkb + rowoff + 4);
    qr[0] = b2f(q0.x); qr[1] = b2f(q0.y); qr[2] = b2f(q0.z); qr[3] = b2f(q0.w);
    qr[4] = b2f(q1.x); qr[5] = b2f(q1.y); qr[6] = b2f(q1.z); qr[7] = b2f(q1.w);
  }
  float stv[8][8];
  float dots[8];
#pragma unroll
  for (int n = 0; n < 8; n++) {
    const float* sr = stk + (((size_t)t * 8 + n) * BB + b) * DIM + d0;
    *(float4*)&stv[n][0] = *(const float4*)(sr);
    *(float4*)&stv[n][4] = *(const float4*)(sr + 4);
    float s = 0;
#pragma unroll
    for (int j = 0; j < 8; j++) s += stv[n][j] * qr[j];
    dots[n] = wsum(s);
  }
  float sb = sbias[(size_t)t * BB + b];
  const float inv = 0.04419417382415922f;  // 1/sqrt(512)
  float sc[8], e[8];
  float mx = -1e30f;
#pragma unroll
  for (int n = 0; n < 8; n++) { sc[n] = (dots[n] + sb) * inv; mx = fmaxf(mx, sc[n]); }
  float den = 0;
#pragma unroll
  for (int n = 0; n < 8; n++) { e[n] = expf(sc[n] - mx); den += e[n]; }
  float rden = 1.0f / den;
  float wv[8];
#pragma unroll
  for (int n = 0; n < 8; n++) wv[n] = e[n] * rden;
  float wsel = 0;
#pragma unroll
  for (int n = 0; n < 8; n++) wsel = (lane == n) ? wv[n] : wsel;
  if (lane < 8) wout[((size_t)t * BB + b) * 8 + lane] = wsel;
  float g[8];
#pragma unroll
  for (int j = 0; j < 8; j++) {
    float s = 0;
#pragma unroll
    for (int n = 0; n < 8; n++) s += wv[n] * stv[n][j];
    g[j] = s;
  }
  float* go = gated + rowoff;
  *(float4*)(go) = *(float4*)&g[0];
  *(float4*)(go + 4) = *(float4*)&g[4];
}

// ============================ host launcher ==================================
extern "C" void kernel_launch(void* const* d_in, const int* in_sizes, int n_in,
                              void* d_out, int out_size, void* d_ws, size_t ws_size,
                              hipStream_t stream) {
  const float* ti  = (const float*)d_in[0];
  const float* sw1 = (const float*)d_in[1];
  const float* sb1 = (const float*)d_in[2];
  const float* sw2 = (const float*)d_in[3];
  const float* sb2 = (const float*)d_in[4];
  const float* sg  = (const float*)d_in[5];
  const float* sbt = (const float*)d_in[6];
  const float* tw1 = (const float*)d_in[7];
  const float* tb1 = (const float*)d_in[8];
  const float* tw2 = (const float*)d_in[9];
  const float* tb2 = (const float*)d_in[10];
  const float* tg  = (const float*)d_in[11];
  const float* tbt = (const float*)d_in[12];
  const float* qw  = (const float*)d_in[13];
  const float* qb  = (const float*)d_in[14];
  const float* kw  = (const float*)d_in[15];
  const float* kb  = (const float*)d_in[16];

  float* out = (float*)d_out;
  float* gated   = out;                                   // T*B*D
  float* weights = out + (size_t)TT * BB * DIM;           // T*B*8
  float* stacked = weights + (size_t)TT * BB * 8;         // T*8*B*D

  char* ws = (char*)d_ws;
  u16*   tib   = (u16*)(ws);                    // 16,777,216
  u16*   xsb   = (u16*)(ws + 16777216);         //  4,194,304
  u16*   w1t   = (u16*)(ws + 20971520);         // 20,971,520
  u16*   w2t   = (u16*)(ws + 41943040);         // 20,971,520
  u16*   qwb   = (u16*)(ws + 62914560);         //  2,097,152
  u16*   kwb   = (u16*)(ws + 65011712);         //  2,097,152
  u16*   mt    = (u16*)(ws + 67108864);         //  2,097,152
  float* sbias = (float*)(ws + 69206016);       //     65,536
  float* qwkb  = (float*)(ws + 69271552);       //      8,192
  float* kwqb  = (float*)(ws + 69279744);       //      8,192
  float* kbqb  = (float*)(ws + 69287936);       //      1,024
  u16*   qkb   = (u16*)(ws + 69288960);         // 16,777,216
  u16*   hbuf  = (u16*)(ws + 86066176);         // SR*HDIM*2*20

  const size_t hoff = 86066176;
  int SR = 512;
  if (ws_size >= hoff + (size_t)NEXP * BB * HDIM * 2) SR = BB;           // 254 MB
  else if (ws_size >= hoff + (size_t)NEXP * 1024 * HDIM * 2) SR = 1024;  // 128 MB

  // weight / gate preprocessing
  k_tcast<<<dim3(32, 16, 4), 256, 0, stream>>>(sw1, w1t, DIM, HDIM);
  k_tcast<<<dim3(32, 16, 16), 256, 0, stream>>>(tw1, w1t + (size_t)4 * HDIM * DIM, DIM, HDIM);
  k_tcast<<<dim3(16, 32, 4), 256, 0, stream>>>(sw2, w2t, HDIM, DIM);
  k_tcast<<<dim3(16, 32, 16), 256, 0, stream>>>(tw2, w2t + (size_t)4 * DIM * HDIM, HDIM, DIM);
  k_cast<<<1024, 256, 0, stream>>>(qw, qwb);
  k_cast<<<1024, 256, 0, stream>>>(kw, kwb);
  k_biasvec<<<1025, 256, 0, stream>>>(qw, kb, kw, qb, qwkb, kwqb, kbqb);
  k_prep<<<1024, 256, 0, stream>>>(ti, qwkb, kbqb, tib, xsb, sbias);
  k_gemm_mt<<<dim3(4, 4, 4), 256, 0, stream>>>(kwb, qwb, mt);

  // expert FFNs: single dispatch pair when workspace allows (ws ~1.2 GB)
  for (int row0 = 0; row0 < BB; row0 += SR) {
    k_gemm_up<<<dim3(8, SR / 128, NEXP), 256, 0, stream>>>(xsb, tib, w1t, sb1, tb1,
                                                           hbuf, row0, SR);
    k_down_ln<<<dim3(SR / 64, 1, NEXP), 512, 0, stream>>>(hbuf, w2t, sb2, tb2,
                                                          xsb, tib, sg, sbt, tg, tbt,
                                                          stacked, row0, SR);
  }

  k_gemm_qk<<<dim3(4, 32, 4), 256, 0, stream>>>(tib, mt, kwqb, qkb);
  k_score<<<4096, 256, 0, stream>>>(stacked, qkb, sbias, gated, weights);
}